// Round 1
// 2443.983 us; speedup vs baseline: 3.0833x; 3.0833x over previous
//
#include <hip/hip_runtime.h>
#include <hip/hip_bf16.h>
#include <stdint.h>

// ---------------------------------------------------------------------------
// QLSTM  (T=512, B=64, D=1024, H=1024)
//   Phase 1: Gx = x @ Wx + b      -- parallel bf16 MFMA GEMM [32768x1024]@[1024x4096]
//   Phase 2: persistent kernel, 512 steps:
//              gates = Gx[t] + h @ Wh   (Wh resident in LDS, 128KB/block)
//              c = f*c + i*g ; h = o*tanh(c)   (fp32 state in registers)
//   Round-2 protocol: all cross-block h traffic uses RELAXED/AGENT (sc1,
//   write-through) accesses -> no buffer_wbl2 / buffer_inv on the 512-step
//   critical path.  __syncthreads() drains every wave's vmcnt (compiler emits
//   s_waitcnt vmcnt(0) before s_barrier), so after the barrier all sc1 h
//   stores are at the coherence point and tid0 publishes with a relaxed flag
//   store.  h is reloaded once per BLOCK (not per wave) into a 32KB LDS tile
//   (XOR-chunk swizzle for conflict-free ds_read_b128 A-frags).
// ---------------------------------------------------------------------------

typedef unsigned short u16;
typedef __attribute__((ext_vector_type(8))) short s16x8;   // bf16x8 MFMA frag (4 VGPRs)
typedef __attribute__((ext_vector_type(4))) float f32x4;   // MFMA accumulator

static constexpr int T_ = 512, B_ = 64, D_ = 1024, H_ = 1024;
static constexpr int MX_ = T_ * B_;      // 32768 rows of x_flat
static constexpr int NG_ = 4 * H_;       // 4096 gate cols

__device__ __forceinline__ u16 f2bf(float f) {
  union { __hip_bfloat16 b; u16 u; } v;
  v.b = __float2bfloat16(f);
  return v.u;
}
__device__ __forceinline__ float bf2f(u16 u) {
  union { __hip_bfloat16 b; u16 u; } v;
  v.u = u;
  return __bfloat162float(v.b);
}

__device__ __forceinline__ void gload_lds16(const u16* g, u16* l) {
  __builtin_amdgcn_global_load_lds(
      (const __attribute__((address_space(1))) unsigned int*)(g),
      (__attribute__((address_space(3))) unsigned int*)(l), 16, 0, 0);
}

__device__ __forceinline__ float sigm(float x) {
  return __builtin_amdgcn_rcpf(1.f + __expf(-x));
}
__device__ __forceinline__ float tanh_(float x) {
  return 2.f * __builtin_amdgcn_rcpf(1.f + __expf(-2.f * x)) - 1.f;
}

__device__ __forceinline__ float gxload(const float* p) { return *p; }
__device__ __forceinline__ float gxload(const u16* p) { return bf2f(*p); }
__device__ __forceinline__ void gxstore(float* p, float v) { *p = v; }
__device__ __forceinline__ void gxstore(u16* p, float v) { *p = f2bf(v); }

// ---------------------------------------------------------------------------
// x (fp32) -> bf16, 8 elems/thread
__global__ __launch_bounds__(256) void k_cast_x(const float* __restrict__ x,
                                                u16* __restrict__ xb) {
  size_t i = ((size_t)blockIdx.x * 256 + threadIdx.x) * 8;
  const float4* xp = (const float4*)(x + i);
  float4 a = xp[0], b = xp[1];
  s16x8 o;
  o[0] = (short)f2bf(a.x); o[1] = (short)f2bf(a.y);
  o[2] = (short)f2bf(a.z); o[3] = (short)f2bf(a.w);
  o[4] = (short)f2bf(b.x); o[5] = (short)f2bf(b.y);
  o[6] = (short)f2bf(b.z); o[7] = (short)f2bf(b.w);
  *(s16x8*)(xb + i) = o;
}

// ---------------------------------------------------------------------------
// Weight prep (unchanged; mapping verified by passing bench):
//  wxt [4096 n][1024 k] bf16 :  wxt[n][k] = W_{n>>10}[k][n&1023]
//  whr [64 g][64 c][1024 k] bf16, c: gate=c&3, hcol_local=(c>>4)*4+((c>>2)&3)
//  biasf [4096] fp32
__global__ __launch_bounds__(256) void k_prep_w(
    const float* __restrict__ Wf, const float* __restrict__ Wi,
    const float* __restrict__ Wg, const float* __restrict__ Wo,
    const float* __restrict__ bf_, const float* __restrict__ bi_,
    const float* __restrict__ bg_, const float* __restrict__ bo_,
    u16* __restrict__ wxt, u16* __restrict__ whr, float* __restrict__ biasf) {
  const int bid = blockIdx.x;            // 0..4095
  const int t = threadIdx.x;
  const float* Ws[4] = {Wf, Wi, Wg, Wo};
  {
    const float* src = Ws[bid >> 10];
    const int col = bid & 1023;
#pragma unroll
    for (int it = 0; it < 4; ++it) {
      int k = t + it * 256;
      wxt[(size_t)bid * 1024 + k] = f2bf(src[(size_t)k * 1024 + col]);
    }
  }
  {
    const int g = bid >> 6, c = bid & 63;
    const float* src = Ws[c & 3];
    const int col = g * 16 + ((c >> 4) << 2) + ((c >> 2) & 3);
#pragma unroll
    for (int it = 0; it < 4; ++it) {
      int k = t + it * 256;
      whr[(size_t)bid * 1024 + k] = f2bf(src[(size_t)(1024 + k) * 1024 + col]);
    }
  }
  if (t == 0) {
    const float* bs[4] = {bf_, bi_, bg_, bo_};
    biasf[bid] = bs[bid >> 10][bid & 1023];
  }
}

// ---------------------------------------------------------------------------
// Gx = x_bf16 @ WxT^T + bias.  m97-style 128x128 tile, BK=32, 256 threads.
template <typename GT>
__global__ __launch_bounds__(256) void k_gemm_gx(
    const u16* __restrict__ A,    // [32768][1024]
    const u16* __restrict__ Bt,   // [4096][1024]
    const float* __restrict__ biasf,
    GT* __restrict__ C) {         // [32768][4096]
  __shared__ u16 aLds[128 * 32];
  __shared__ u16 bLds[128 * 32];
  const int tid = threadIdx.x;
  const int w = tid >> 6, l = tid & 63;
  const int q = l >> 4, cc = l & 15;
  const int bm = blockIdx.x, bn = blockIdx.y;
  const int wm = (w & 1) * 64, wn = (w >> 1) * 64;
  const int lrow = l >> 2, lchunk = (l & 3) * 8;

  f32x4 zero = {0.f, 0.f, 0.f, 0.f};
  f32x4 acc[4][4];
#pragma unroll
  for (int i = 0; i < 4; ++i)
#pragma unroll
    for (int j = 0; j < 4; ++j) acc[i][j] = zero;

  for (int k0 = 0; k0 < 1024; k0 += 32) {
#pragma unroll
    for (int r = 0; r < 2; ++r) {
      gload_lds16(A + (size_t)(bm * 128 + r * 64 + w * 16 + lrow) * 1024 + k0 + lchunk,
                  &aLds[(r * 64 + w * 16) * 32]);
      gload_lds16(Bt + (size_t)(bn * 128 + r * 64 + w * 16 + lrow) * 1024 + k0 + lchunk,
                  &bLds[(r * 64 + w * 16) * 32]);
    }
    __syncthreads();
    s16x8 af[4], bf[4];
#pragma unroll
    for (int i = 0; i < 4; ++i)
      af[i] = *(const s16x8*)&aLds[(wm + i * 16 + cc) * 32 + q * 8];
#pragma unroll
    for (int j = 0; j < 4; ++j)
      bf[j] = *(const s16x8*)&bLds[(wn + j * 16 + cc) * 32 + q * 8];
#pragma unroll
    for (int i = 0; i < 4; ++i)
#pragma unroll
      for (int j = 0; j < 4; ++j)
        acc[i][j] = __builtin_amdgcn_mfma_f32_16x16x32_bf16(af[i], bf[j], acc[i][j], 0, 0, 0);
    __syncthreads();
  }
#pragma unroll
  for (int i = 0; i < 4; ++i) {
    const int row0 = bm * 128 + wm + i * 16 + q * 4;
#pragma unroll
    for (int j = 0; j < 4; ++j) {
      const int col = bn * 128 + wn + j * 16 + cc;
      const float bb = biasf[col];
#pragma unroll
      for (int r = 0; r < 4; ++r)
        gxstore(C + (size_t)(row0 + r) * 4096 + col, acc[i][j][r] + bb);
    }
  }
}

// ---------------------------------------------------------------------------
// Persistent recurrent kernel. 256 blocks x 256 threads, 160KB LDS.
// block: m = bid>>6 (batch tile of 16), g = bid&63 (16 h-cols -> 64 gate cols).
// Flags are padded to one 128B line each: flags[m*2048 + g*32].
template <typename GT>
__global__ __launch_bounds__(256, 1) void k_lstm(
    const u16* __restrict__ Whr,   // [64][64][1024]
    const GT* __restrict__ Gx,     // [32768][4096]
    u16* __restrict__ hbuf,        // [2][64][1024] bf16 (buf 0 zeroed)
    float* __restrict__ out,       // stacked [512][64][1024], hT, cT
    unsigned* __restrict__ flags) {// [4][64*32] zeroed (128B-padded flags)
  // Wh resident in LDS. chunk (kk,q,col) at [(kk*4+q)*64 + col].
  __shared__ s16x8 wl[32 * 4 * 64];            // 128 KB
  // h tile: 16 rows x 1024 cols bf16, stored as 16B chunks with
  // chunk' = chunk ^ (row&7)  (swizzle applied on the GLOBAL source address;
  // LDS writes are linear -> both-sides involution, conflict-free reads).
  __shared__ u16 hl[16 * 1024];                // 32 KB
  const int tid = threadIdx.x;
  const int w = tid >> 6, l = tid & 63, q = l >> 4, cc = l & 15;
  const int m = blockIdx.x >> 6, g = blockIdx.x & 63;
  const int gate = cc & 3;
  const int hcol = g * 16 + w * 4 + (cc >> 2);
  const int gxcol = gate * 1024 + hcol;
  const int wcol = w * 16 + cc;                // this lane's B-frag column
  unsigned* gflag = flags + m * (64 * 32);

  // ---- stage Wh into LDS once (coalesced global reads) ----
  {
    const int col = tid >> 2;                  // 0..63
    const int kb = (tid & 3) * 256;            // k base
    const u16* src = Whr + (size_t)(g * 64 + col) * 1024 + kb;
#pragma unroll
    for (int i = 0; i < 8; ++i) {
      const int kk = kb / 32 + i;
#pragma unroll
      for (int qq = 0; qq < 4; ++qq)
        wl[(kk * 4 + qq) * 64 + col] = *(const s16x8*)(src + i * 32 + qq * 8);
    }
  }

  // ---- per-lane swizzled A-frag read bases ----
  // frag I needs global chunk j = q + 4*I of row cc; it lives at LDS chunk
  // J = j ^ (cc&7) = (q^(cc&3)) + 4*((I&1)^xb) + 8*(I>>1),  xb=(cc>>2)&1.
  const int xb = (cc >> 2) & 1;
  const u16* hb0 = hl + cc * 1024 + ((q ^ (cc & 3)) + 4 * xb) * 8;       // I even
  const u16* hb1 = hl + cc * 1024 + ((q ^ (cc & 3)) + 4 * (1 - xb)) * 8; // I odd

  // ---- cooperative block-wide h refill: global (sc1) -> LDS ----
  // shot s: linear chunk c = s*256+tid; row r=c>>7, pos p=c&127.
  // Load global chunk p^(r&7) of row r, ds_write linearly at chunk c.
  auto refill = [&](int buf) {
    const u16* hsrc = hbuf + (size_t)buf * (B_ * H_) + (size_t)m * 16 * 1024;
    unsigned long long vb[16];
#pragma unroll
    for (int s = 0; s < 8; ++s) {
      const int c = s * 256 + tid;
      const int r = c >> 7, p = c & 127;
      const unsigned long long* src =
          (const unsigned long long*)(hsrc + r * 1024 + (p ^ (r & 7)) * 8);
      vb[2 * s] = __hip_atomic_load(src, __ATOMIC_RELAXED, __HIP_MEMORY_SCOPE_AGENT);
      vb[2 * s + 1] =
          __hip_atomic_load(src + 1, __ATOMIC_RELAXED, __HIP_MEMORY_SCOPE_AGENT);
    }
#pragma unroll
    for (int s = 0; s < 8; ++s) {
      union { unsigned long long u[2]; s16x8 v; } t2;
      t2.u[0] = vb[2 * s]; t2.u[1] = vb[2 * s + 1];
      *(s16x8*)(hl + (s * 256 + tid) * 8) = t2.v;
    }
  };

  float cst[4] = {0.f, 0.f, 0.f, 0.f};
  float hlast[4] = {0.f, 0.f, 0.f, 0.f};

  // prefetch Gx for t=0
  float gxv[4];
  {
    const GT* gp = Gx + (size_t)(m * 16 + q * 4) * 4096 + gxcol;
#pragma unroll
    for (int r = 0; r < 4; ++r) gxv[r] = gxload(gp + (size_t)r * 4096);
  }

  refill(0);            // h0 = 0 (hbuf[0] zeroed; visible via kernel boundary)
  __syncthreads();      // wl + hl ready

#define BFRAG(kk) (wl[((kk) * 4 + q) * 64 + wcol])

  int polldead = 0;

  for (int t = 0; t < T_; ++t) {
    f32x4 acc0 = {0.f, 0.f, 0.f, 0.f}, acc1 = {0.f, 0.f, 0.f, 0.f};
#pragma unroll
    for (int I = 0; I < 32; I += 2) {
      s16x8 a0 = *(const s16x8*)(hb0 + (I >> 1) * 64);
      s16x8 a1 = *(const s16x8*)(hb1 + (I >> 1) * 64);
      acc0 = __builtin_amdgcn_mfma_f32_16x16x32_bf16(a0, BFRAG(I), acc0, 0, 0, 0);
      acc1 = __builtin_amdgcn_mfma_f32_16x16x32_bf16(a1, BFRAG(I + 1), acc1, 0, 0, 0);
    }

    float v0[4];
#pragma unroll
    for (int r = 0; r < 4; ++r) {
      float x = acc0[r] + acc1[r] + gxv[r];
      v0[r] = (gate == 2) ? tanh_(x) : sigm(x);
    }
#pragma unroll
    for (int r = 0; r < 4; ++r) {
      float a0 = v0[r];
      float a1 = __shfl_xor(a0, 1);
      float a2 = __shfl_xor(a0, 2);
      float a3 = __shfl_xor(a1, 2);
      float fv = (gate == 0) ? a0 : (gate == 1) ? a1 : (gate == 2) ? a2 : a3;
      float iv = (gate == 0) ? a1 : (gate == 1) ? a0 : (gate == 2) ? a3 : a2;
      float gv = (gate == 0) ? a2 : (gate == 1) ? a3 : (gate == 2) ? a0 : a1;
      float ov = (gate == 0) ? a3 : (gate == 1) ? a2 : (gate == 2) ? a1 : a0;
      float cn = fv * cst[r] + iv * gv;
      cst[r] = cn;
      hlast[r] = ov * tanh_(cn);
    }

    // ---- h -> hbuf[(t+1)&1]: device-visible write-through stores (sc1) ----
    if (gate == 0) {
      u16* hd = hbuf + (size_t)((t + 1) & 1) * (B_ * H_);
#pragma unroll
      for (int r = 0; r < 4; ++r) {
        const int row = m * 16 + q * 4 + r;
        __hip_atomic_store(hd + row * 1024 + hcol, f2bf(hlast[r]),
                           __ATOMIC_RELAXED, __HIP_MEMORY_SCOPE_AGENT);
      }
    }
    // __syncthreads drains every wave's vmcnt before s_barrier -> all sc1
    // h stores are at the coherence point when any lane passes this barrier.
    __syncthreads();
    if (tid == 0)
      __hip_atomic_store(&gflag[g * 32], (unsigned)(t + 1), __ATOMIC_RELAXED,
                         __HIP_MEMORY_SCOPE_AGENT);
    asm volatile("" ::: "memory");   // keep the publish ahead of the tail work

    // Gx prefetch for t+1 (off the publish path; drains during the spin)
    float gxn[4];
    {
      const int tn = (t + 1) & 511;
      const GT* gp = Gx + (size_t)(tn * 64 + m * 16 + q * 4) * 4096 + gxcol;
#pragma unroll
      for (int r = 0; r < 4; ++r) gxn[r] = gxload(gp + (size_t)r * 4096);
    }
    // stacked-h output (plain stores; off the publish path; flushed at kernel end)
    if (gate == 0) {
#pragma unroll
      for (int r = 0; r < 4; ++r) {
        const int row = m * 16 + q * 4 + r;
        out[(size_t)(t * 64 + row) * 1024 + hcol] = hlast[r];
      }
    }

    // -------- per-group flag-vector wait (wave 0 polls 64 padded flags) ----
    if (w == 0 && !polldead) {
      const unsigned* fp = gflag + l * 32;
      for (unsigned it = 0;; ++it) {
        unsigned v = __hip_atomic_load(fp, __ATOMIC_RELAXED,
                                       __HIP_MEMORY_SCOPE_AGENT);
        if (__all(v > (unsigned)t)) break;
        if (it > (1u << 22)) { polldead = 1; break; }   // safety: no hangs
        __builtin_amdgcn_s_sleep(1);
      }
    }
    __syncthreads();   // all waves: peer h for t+1 is globally visible

    refill((t + 1) & 1);   // block-wide 32KB reload (sc1 loads bypass stale L1/L2)
    __syncthreads();       // hl ready for t+1

#pragma unroll
    for (int r = 0; r < 4; ++r) gxv[r] = gxn[r];
  }
#undef BFRAG

  if (gate == 0) {
    float* hT = out + (size_t)T_ * B_ * H_;
    float* cT = hT + B_ * H_;
#pragma unroll
    for (int r = 0; r < 4; ++r) {
      const int row = m * 16 + q * 4 + r;
      hT[row * 1024 + hcol] = hlast[r];
      cT[row * 1024 + hcol] = cst[r];
    }
  }
}

// ---------------------------------------------------------------------------
extern "C" void kernel_launch(void* const* d_in, const int* in_sizes, int n_in,
                              void* d_out, int out_size, void* d_ws, size_t ws_size,
                              hipStream_t stream) {
  (void)in_sizes; (void)n_in; (void)out_size;
  const float* x   = (const float*)d_in[0];
  const float* Wf  = (const float*)d_in[1];
  const float* bf_ = (const float*)d_in[2];
  const float* Wi  = (const float*)d_in[3];
  const float* bi_ = (const float*)d_in[4];
  const float* Wg  = (const float*)d_in[5];
  const float* bg_ = (const float*)d_in[6];
  const float* Wo  = (const float*)d_in[7];
  const float* bo_ = (const float*)d_in[8];
  float* out = (float*)d_out;

  uint8_t* ws = (uint8_t*)d_ws;
  const size_t n_gx    = (size_t)MX_ * NG_;
  const size_t sz_xb   = (size_t)MX_ * 1024 * 2;   // 64 MB
  const size_t sz_wxt  = (size_t)4096 * 1024 * 2;  // 8 MB
  const size_t sz_whr  = (size_t)4096 * 1024 * 2;  // 8 MB
  const size_t sz_bias = 4096 * 4;
  const size_t sz_hbuf = (size_t)2 * 64 * 1024 * 2;
  const size_t sz_ctrl = 4 * 64 * 32 * 4 + 8192;   // padded flags [4][64*32] + pad
  const size_t fixed = sz_xb + sz_wxt + sz_whr + sz_bias + sz_hbuf + sz_ctrl + 1024;
  const bool f32gx = ws_size >= fixed + n_gx * 4;  // fp32 Gx (512 MB) if it fits
  const size_t sz_gx = n_gx * (f32gx ? 4 : 2);

  size_t off = 0;
  uint8_t* p_gx   = ws;                  off += sz_gx;
  u16*     xb     = (u16*)(ws + off);    off += sz_xb;
  u16*     wxt    = (u16*)(ws + off);    off += sz_wxt;
  u16*     whr    = (u16*)(ws + off);    off += sz_whr;
  float*   biasf  = (float*)(ws + off);  off += sz_bias;
  u16*     hbuf   = (u16*)(ws + off);    off += sz_hbuf;
  unsigned* flags = (unsigned*)(ws + off);

  // zero h0 (both h buffers) + barrier flags (contiguous)
  hipMemsetAsync(hbuf, 0, sz_hbuf + sz_ctrl, stream);
  k_cast_x<<<(MX_ * 1024) / (256 * 8), 256, 0, stream>>>(x, xb);
  k_prep_w<<<4096, 256, 0, stream>>>(Wf, Wi, Wg, Wo, bf_, bi_, bg_, bo_, wxt, whr, biasf);
  if (f32gx) {
    k_gemm_gx<float><<<dim3(256, 32), 256, 0, stream>>>(xb, wxt, biasf, (float*)p_gx);
    k_lstm<float><<<256, 256, 0, stream>>>(whr, (const float*)p_gx, hbuf, out, flags);
  } else {
    k_gemm_gx<u16><<<dim3(256, 32), 256, 0, stream>>>(xb, wxt, biasf, (u16*)p_gx);
    k_lstm<u16><<<256, 256, 0, stream>>>(whr, (const u16*)p_gx, hbuf, out, flags);
  }
}